// Round 7
// baseline (146.636 us; speedup 1.0000x reference)
//
#include <hip/hip_runtime.h>
#include <hip/hip_bf16.h>
#include <math.h>

#define BATCH  64
#define SEQ    2048
#define DMODEL 512
#define ATT    256
#define M_TOTAL (BATCH * SEQ)

#define MT     256                      // rows per block (scores GEMM)
#define KC     32                       // k per chunk
#define NCHUNK 16
#define CHUNK_USH (ATT * KC)            // 8192 ushorts = 16 KB per tile
#define WA_LO_OFF (NCHUNK * CHUNK_USH)  // 131072 ushorts

// d_ws layout
#define XH_OFF    (1u << 20)                          // 1 MB (wa_cvt lives below)
#define XH_BYTES  ((size_t)M_TOTAL * DMODEL * 2)      // 128 MB bf16 X-hi
#define PART_OFF  (XH_OFF + XH_BYTES)
#define PART_BYTES ((size_t)8 * BATCH * DMODEL * 4)   // 1 MB
#define WS_NEED   (PART_OFF + PART_BYTES)

typedef __attribute__((ext_vector_type(8))) short short8v;
typedef __attribute__((ext_vector_type(4))) float floatx4;

__device__ __forceinline__ ushort f2bf_rne(float f) {
    unsigned u = __float_as_uint(f);
    u += 0x7FFFu + ((u >> 16) & 1u);
    return (ushort)(u >> 16);
}
__device__ __forceinline__ float bf2f(ushort h) {
    return __uint_as_float(((unsigned)h) << 16);
}
__device__ __forceinline__ void gll16(const void* g, void* l) {
    __builtin_amdgcn_global_load_lds(
        (const __attribute__((address_space(1))) unsigned*)g,
        (__attribute__((address_space(3))) unsigned*)l, 16, 0, 0);
}
// sign-free fast tanh: 1 - 2/(e^{2x}+1); exact at +-inf, 0
__device__ __forceinline__ float fast_tanh(float x) {
    return 1.0f - 2.0f * __builtin_amdgcn_rcpf(__expf(x + x) + 1.0f);
}
// float4 -> packed bf16 hi (truncation) + lo (RNE of remainder)
__device__ __forceinline__ void cvt4(float4 v, uint2& hi, uint2& lo) {
    unsigned u0 = __float_as_uint(v.x), u1 = __float_as_uint(v.y);
    unsigned u2 = __float_as_uint(v.z), u3 = __float_as_uint(v.w);
    hi.x = __builtin_amdgcn_perm(u1, u0, 0x07060302u);   // [bf(y):bf(x)]
    hi.y = __builtin_amdgcn_perm(u3, u2, 0x07060302u);
    float r0 = v.x - __uint_as_float(u0 & 0xFFFF0000u);
    float r1 = v.y - __uint_as_float(u1 & 0xFFFF0000u);
    float r2 = v.z - __uint_as_float(u2 & 0xFFFF0000u);
    float r3 = v.w - __uint_as_float(u3 & 0xFFFF0000u);
    asm("v_cvt_pk_bf16_f32 %0, %1, %2" : "=v"(lo.x) : "v"(r0), "v"(r1));
    asm("v_cvt_pk_bf16_f32 %0, %1, %2" : "=v"(lo.y) : "v"(r2), "v"(r3));
}

// K0: Wa fp32 [256][512] -> bf16 hi/lo per-chunk quad-major LDS images:
// elem (a, k): chunk kc=k>>5, quad q=(k&31)>>3 -> kc*8192 + (q*256+a)*8 + (k&7)
__global__ __launch_bounds__(256)
void wa_convert_kernel(const float* __restrict__ Wa, ushort* __restrict__ out) {
    int idx = blockIdx.x * 256 + threadIdx.x;   // 131072
    float x = Wa[idx];
    ushort hi = f2bf_rne(x);
    ushort lo = f2bf_rne(x - bf2f(hi));
    int a = idx >> 9, k = idx & 511;
    int kc = k >> 5, kk = k & 31, q = kk >> 3;
    size_t o = (size_t)kc * CHUNK_USH + (size_t)(q * 256 + a) * 8 + (kk & 7);
    out[o] = hi;
    out[WA_LO_OFF + o] = lo;
}

// one A-row stage: convert one float4 (row r of chunk), write LDS + Xh (r added once)
__device__ __forceinline__ void stage_row(ushort* nb, float4 v, int r, int chunk,
                                          ushort* xh_base, int sc) {
    ushort* ahp = nb;
    ushort* alp = nb + CHUNK_USH;
    const int q = sc >> 1, h = (sc & 1) * 4;
    uint2 hi, lo;
    cvt4(v, hi, lo);
    *(uint2*)&ahp[(q * 256 + r) * 8 + h] = hi;
    *(uint2*)&alp[(q * 256 + r) * 8 + h] = lo;
    if (xh_base)
        *(uint2*)&xh_base[(size_t)r * DMODEL + chunk * KC + sc * 4] = hi;
}
// B-chunk staging: 4 gll16 per thread (linear copy of prebuilt swizzled image)
__device__ __forceinline__ void gll_b(ushort* nb, int chunk,
                                      const ushort* __restrict__ wa_cvt,
                                      int wid, int l) {
    ushort* bh = nb + 2 * CHUNK_USH;
    ushort* bl = nb + 3 * CHUNK_USH;
    const char* ghi = (const char*)(wa_cvt + (size_t)chunk * CHUNK_USH);
    const char* glo = (const char*)(wa_cvt + (size_t)WA_LO_OFF + (size_t)chunk * CHUNK_USH);
    #pragma unroll
    for (int i = 0; i < 2; ++i) {
        int seg = wid * 2 + i;                  // 16 segs x 1 KB per tile
        gll16(ghi + seg * 1024 + l * 16, (char*)bh + seg * 1024);
        gll16(glo + seg * 1024 + l * 16, (char*)bl + seg * 1024);
    }
}

#define SB() __builtin_amdgcn_sched_barrier(0)
// 3-term split MFMA for one output column-block nj
#define MFMA3(nj, BH, BV)                                                           \
    {                                                                               \
        _Pragma("unroll")                                                           \
        for (int mi = 0; mi < 4; ++mi) {                                            \
            acc[mi][nj] = __builtin_amdgcn_mfma_f32_16x16x32_bf16(av[mi], BH, acc[mi][nj], 0, 0, 0); \
            acc[mi][nj] = __builtin_amdgcn_mfma_f32_16x16x32_bf16(ah[mi], BV, acc[mi][nj], 0, 0, 0); \
            acc[mi][nj] = __builtin_amdgcn_mfma_f32_16x16x32_bf16(ah[mi], BH, acc[mi][nj], 0, 0, 0); \
        }                                                                           \
    }

// K1: z[m] = sum_a tanh(X[m]·Wa[a] + ba[a]) * ae[a], split-bf16 3-term MFMA.
// 512 thr / 8 waves, tile 256x256, double-buffered LDS, 1 barrier per chunk,
// 4-phase MFMA/ds_read/stage interleave + setprio (T3/T4/T5).
__global__ __launch_bounds__(512, 2)
void scores_mfma_kernel(const float* __restrict__ X,
                        const ushort* __restrict__ wa_cvt,
                        const float* __restrict__ ba,
                        const float* __restrict__ ae,
                        float* __restrict__ z,
                        ushort* __restrict__ Xh) {
    __shared__ __align__(16) ushort pool[8 * CHUNK_USH];   // 128 KiB

    const int tid = threadIdx.x;
    const int l   = tid & 63;
    const int wid = tid >> 6;
    const int wm  = wid >> 1, wn = wid & 1;
    const int n   = l & 15,   g  = l >> 4;
    const int m0  = blockIdx.x * MT;
    const int sr  = tid >> 3;       // staging base row (0..63)
    const int sc  = tid & 7;        // staging 16B col-quad

    // coalesced X source: wave = 8 rows x 128B full lines
    const float4* xq = (const float4*)(X + (size_t)(m0 + sr) * DMODEL) + sc;
    ushort* xh_base = Xh ? (Xh + (size_t)m0 * DMODEL) : nullptr;  // r added in stage

    // frag offsets in quad-major tile: (g*256 + row)*8 ushorts
    int aoff[4], boff[8];
    #pragma unroll
    for (int mi = 0; mi < 4; ++mi) aoff[mi] = g * 2048 + (wm * 64 + mi * 16 + n) * 8;
    #pragma unroll
    for (int nj = 0; nj < 8; ++nj) boff[nj] = g * 2048 + (wn * 128 + nj * 16 + n) * 8;

    floatx4 acc[4][8];
    #pragma unroll
    for (int i = 0; i < 4; ++i)
        #pragma unroll
        for (int j = 0; j < 8; ++j)
            acc[i][j] = (floatx4){0.f, 0.f, 0.f, 0.f};

    // ---- prologue: stage chunk 0 into buf0, prefetch chunk-1 X ----
    float4 xa[4];
    #pragma unroll
    for (int i = 0; i < 4; ++i) xa[i] = xq[i * 8192];        // chunk 0
    gll_b(pool, 0, wa_cvt, wid, l);
    #pragma unroll
    for (int i = 0; i < 4; ++i)
        stage_row(pool, xa[i], sr + 64 * i, 0, xh_base, sc);
    SB();
    #pragma unroll
    for (int i = 0; i < 4; ++i) xa[i] = xq[8 + i * 8192];    // chunk 1
    SB();
    asm volatile("s_waitcnt vmcnt(4)" ::: "memory");         // glls+stores done; X flies
    __builtin_amdgcn_s_barrier();

    #pragma unroll 1
    for (int kc = 0; kc < NCHUNK; ++kc) {
        const ushort* cb = pool + (kc & 1) * (4 * CHUNK_USH);
        ushort* nb = pool + ((kc + 1) & 1) * (4 * CHUNK_USH);
        const bool do_stage = (kc + 1 < NCHUNK);
        const bool do_xl    = (kc + 2 < NCHUNK);

        const ushort* ah_t = cb;
        const ushort* al_t = cb + CHUNK_USH;
        const ushort* bh_t = cb + 2 * CHUNK_USH;
        const ushort* bl_t = cb + 3 * CHUNK_USH;

        // issue section: A frags + B pair0 + next-chunk gll (max latency cover)
        short8v ah[4], av[4];
        #pragma unroll
        for (int mi = 0; mi < 4; ++mi) {
            ah[mi] = *(const short8v*)&ah_t[aoff[mi]];
            av[mi] = *(const short8v*)&al_t[aoff[mi]];
        }
        short8v b0h = *(const short8v*)&bh_t[boff[0]], b0v = *(const short8v*)&bl_t[boff[0]];
        short8v b1h = *(const short8v*)&bh_t[boff[1]], b1v = *(const short8v*)&bl_t[boff[1]];
        if (do_stage) gll_b(nb, kc + 1, wa_cvt, wid, l);
        SB();

        // phase 0: prefetch B pair1; MFMA pair0; stage rows 0,1
        short8v b2h = *(const short8v*)&bh_t[boff[2]], b2v = *(const short8v*)&bl_t[boff[2]];
        short8v b3h = *(const short8v*)&bh_t[boff[3]], b3v = *(const short8v*)&bl_t[boff[3]];
        __builtin_amdgcn_s_setprio(1);
        MFMA3(0, b0h, b0v);
        MFMA3(1, b1h, b1v);
        __builtin_amdgcn_s_setprio(0);
        if (do_stage) {
            stage_row(nb, xa[0], sr,      kc + 1, xh_base, sc);
            stage_row(nb, xa[1], sr + 64, kc + 1, xh_base, sc);
        }
        SB();

        // phase 1: prefetch B pair2; MFMA pair1; stage rows 2,3
        b0h = *(const short8v*)&bh_t[boff[4]]; b0v = *(const short8v*)&bl_t[boff[4]];
        b1h = *(const short8v*)&bh_t[boff[5]]; b1v = *(const short8v*)&bl_t[boff[5]];
        __builtin_amdgcn_s_setprio(1);
        MFMA3(2, b2h, b2v);
        MFMA3(3, b3h, b3v);
        __builtin_amdgcn_s_setprio(0);
        if (do_stage) {
            stage_row(nb, xa[2], sr + 128, kc + 1, xh_base, sc);
            stage_row(nb, xa[3], sr + 192, kc + 1, xh_base, sc);
        }
        SB();

        // phase 2: prefetch B pair3; MFMA pair2; X prefetch for chunk+2
        b2h = *(const short8v*)&bh_t[boff[6]]; b2v = *(const short8v*)&bl_t[boff[6]];
        b3h = *(const short8v*)&bh_t[boff[7]]; b3v = *(const short8v*)&bl_t[boff[7]];
        __builtin_amdgcn_s_setprio(1);
        MFMA3(4, b0h, b0v);
        MFMA3(5, b1h, b1v);
        __builtin_amdgcn_s_setprio(0);
        if (do_xl) {
            #pragma unroll
            for (int i = 0; i < 4; ++i)
                xa[i] = xq[(kc + 2) * 8 + i * 8192];
        }
        SB();

        // phase 3: MFMA pair3; counted drain + barrier
        __builtin_amdgcn_s_setprio(1);
        MFMA3(6, b2h, b2v);
        MFMA3(7, b3h, b3v);
        __builtin_amdgcn_s_setprio(0);
        SB();
        if (do_stage) {
            if (do_xl)
                asm volatile("s_waitcnt vmcnt(4)" ::: "memory");  // glls+stores done; X flies
            else
                asm volatile("s_waitcnt vmcnt(0)" ::: "memory");
            __builtin_amdgcn_s_barrier();
        }
    }

    __syncthreads();                     // all compute done; pool reusable
    float* zb = (float*)pool;            // [2][256] partial z

    float bav[8], aev[8];
    #pragma unroll
    for (int nj = 0; nj < 8; ++nj) {
        int c = wn * 128 + nj * 16 + n;
        bav[nj] = ba[c];
        aev[nj] = ae[c];
    }
    // C/D map (HW-verified): M-row = wm*64 + mi*16 + g*4 + e, col = wn*128 + nj*16 + n
    #pragma unroll
    for (int mi = 0; mi < 4; ++mi) {
        float zp[4] = {0.f, 0.f, 0.f, 0.f};
        #pragma unroll
        for (int nj = 0; nj < 8; ++nj)
            #pragma unroll
            for (int e = 0; e < 4; ++e)
                zp[e] += fast_tanh(acc[mi][nj][e] + bav[nj]) * aev[nj];
        #pragma unroll
        for (int off = 8; off >= 1; off >>= 1)
            #pragma unroll
            for (int e = 0; e < 4; ++e)
                zp[e] += __shfl_xor(zp[e], off, 64);
        if (n == 0)
            *(float4*)&zb[wn * 256 + wm * 64 + mi * 16 + g * 4] =
                make_float4(zp[0], zp[1], zp[2], zp[3]);
    }
    __syncthreads();
    if (tid < MT)
        z[m0 + tid] = zb[tid] + zb[256 + tid];
}

// K2: in-place softmax over SEQ per batch.
__global__ __launch_bounds__(256)
void softmax_kernel(float* __restrict__ zw) {
    __shared__ float red[4];
    __shared__ float bcast;
    const int b = blockIdx.x, tid = threadIdx.x;
    float* row = zw + (size_t)b * SEQ;

    float zi[8];
    #pragma unroll
    for (int i = 0; i < 8; ++i) zi[i] = row[tid + i * 256];

    float m = -3.0e38f;
    #pragma unroll
    for (int i = 0; i < 8; ++i) m = fmaxf(m, zi[i]);
    #pragma unroll
    for (int off = 32; off >= 1; off >>= 1) m = fmaxf(m, __shfl_xor(m, off, 64));
    if ((tid & 63) == 0) red[tid >> 6] = m;
    __syncthreads();
    if (tid == 0) bcast = fmaxf(fmaxf(red[0], red[1]), fmaxf(red[2], red[3]));
    __syncthreads();
    m = bcast;

    float s = 0.f;
    #pragma unroll
    for (int i = 0; i < 8; ++i) { zi[i] = expf(zi[i] - m); s += zi[i]; }
    #pragma unroll
    for (int off = 32; off >= 1; off >>= 1) s += __shfl_xor(s, off, 64);
    __syncthreads();
    if ((tid & 63) == 0) red[tid >> 6] = s;
    __syncthreads();
    if (tid == 0) bcast = 1.f / (red[0] + red[1] + red[2] + red[3]);
    __syncthreads();
    float inv = bcast;

    #pragma unroll
    for (int i = 0; i < 8; ++i) row[tid + i * 256] = zi[i] * inv;
}

// K3a: bf16 pool partials: partials[sc][b][f] = sum_{s in chunk} w[s]*Xh[b,s,f]
#define PCHUNK 256
__global__ __launch_bounds__(512)
void pool_bf16_kernel(const ushort* __restrict__ Xh, const float* __restrict__ w,
                      float* __restrict__ partials) {
    __shared__ float wl[PCHUNK];
    __shared__ float2 accs[512];
    const int b  = blockIdx.y;
    const int sc = blockIdx.x;       // 0..7
    const int t  = threadIdx.x;
    const int u  = t & 255;          // uint idx: features 2u, 2u+1
    const int p  = t >> 8;           // row parity
    const int s0 = sc * PCHUNK;
    if (t < PCHUNK) wl[t] = w[(size_t)b * SEQ + s0 + t];
    __syncthreads();
    const uint* xp = (const uint*)(Xh + ((size_t)b * SEQ + s0 + p) * DMODEL) + u;
    float a0 = 0.f, a1 = 0.f;
    #pragma unroll 8
    for (int s = 0; s < PCHUNK; s += 2) {
        uint v   = xp[(size_t)s * (DMODEL / 2)];
        float ws = wl[s + p];
        a0 = fmaf(__uint_as_float(v << 16), ws, a0);
        a1 = fmaf(__uint_as_float(v & 0xFFFF0000u), ws, a1);
    }
    accs[t] = make_float2(a0, a1);
    __syncthreads();
    if (t < 256) {
        float2 x0 = accs[t], x1 = accs[t + 256];
        *(float2*)&partials[((size_t)sc * BATCH + b) * DMODEL + 2 * t] =
            make_float2(x0.x + x1.x, x0.y + x1.y);
    }
}

// K3b: out[b][f] = sum_sc partials[sc][b][f]
__global__ __launch_bounds__(512)
void pool_reduce_kernel(const float* __restrict__ partials, float* __restrict__ out) {
    int i = blockIdx.x * 512 + threadIdx.x;   // 32768
    float s = 0.f;
    #pragma unroll
    for (int c = 0; c < 8; ++c)
        s += partials[(size_t)c * BATCH * DMODEL + i];
    out[i] = s;
}

// fallback fp32 pool (if ws too small): needs memset + atomics
__global__ __launch_bounds__(512)
void pool_fp32_kernel(const float* __restrict__ X, const float* __restrict__ w,
                      float* __restrict__ out) {
    __shared__ float wl[PCHUNK];
    const int b  = blockIdx.y;
    const int sc = blockIdx.x;
    const int f  = threadIdx.x;
    const int s0 = sc * PCHUNK;
    if (f < PCHUNK) wl[f] = w[(size_t)b * SEQ + s0 + f];
    __syncthreads();
    const float* xp = X + ((size_t)b * SEQ + s0) * DMODEL + f;
    float a0 = 0.f, a1 = 0.f, a2 = 0.f, a3 = 0.f;
    #pragma unroll 4
    for (int s = 0; s < PCHUNK; s += 4) {
        a0 = fmaf(xp[(size_t)(s + 0) * DMODEL], wl[s + 0], a0);
        a1 = fmaf(xp[(size_t)(s + 1) * DMODEL], wl[s + 1], a1);
        a2 = fmaf(xp[(size_t)(s + 2) * DMODEL], wl[s + 2], a2);
        a3 = fmaf(xp[(size_t)(s + 3) * DMODEL], wl[s + 3], a3);
    }
    atomicAdd(&out[b * DMODEL + f], (a0 + a1) + (a2 + a3));
}

extern "C" void kernel_launch(void* const* d_in, const int* in_sizes, int n_in,
                              void* d_out, int out_size, void* d_ws, size_t ws_size,
                              hipStream_t stream) {
    const float* X  = (const float*)d_in[0];
    const float* Wa = (const float*)d_in[1];
    const float* ba = (const float*)d_in[2];
    const float* ae = (const float*)d_in[3];
    float* out  = (float*)d_out;
    float* feat = out;                       // [64][512]
    float* wgt  = out + BATCH * DMODEL;      // [64][2048]; z pre-softmax

    ushort* wa_cvt = (ushort*)d_ws;          // 512 KB
    const bool big_ws = ws_size >= WS_NEED;
    ushort* Xh      = big_ws ? (ushort*)((char*)d_ws + XH_OFF)  : nullptr;
    float* partials = big_ws ? (float*)((char*)d_ws + PART_OFF) : nullptr;

    wa_convert_kernel<<<ATT * DMODEL / 256, 256, 0, stream>>>(Wa, wa_cvt);
    scores_mfma_kernel<<<M_TOTAL / MT, 512, 0, stream>>>(X, wa_cvt, ba, ae, wgt, Xh);
    softmax_kernel<<<BATCH, 256, 0, stream>>>(wgt);
    if (big_ws) {
        pool_bf16_kernel<<<dim3(SEQ / PCHUNK, BATCH), 512, 0, stream>>>(Xh, wgt, partials);
        pool_reduce_kernel<<<BATCH * DMODEL / 512, 512, 0, stream>>>(partials, feat);
    } else {
        hipMemsetAsync(feat, 0, BATCH * DMODEL * sizeof(float), stream);
        pool_fp32_kernel<<<dim3(SEQ / PCHUNK, BATCH), 512, 0, stream>>>(X, wgt, feat);
    }
}